// Round 8
// baseline (126.504 us; speedup 1.0000x reference)
//
#include <hip/hip_runtime.h>
#include <hip/hip_bf16.h>

typedef __bf16 bf16x8 __attribute__((ext_vector_type(8)));
typedef unsigned short u16x8 __attribute__((ext_vector_type(8)));
typedef unsigned short u16x4 __attribute__((ext_vector_type(4)));
typedef float f32x4 __attribute__((ext_vector_type(4)));
typedef unsigned short u16;

constexpr int DIMc = 256, Tt = 2048, Kk = 1024, Dd = 64;

// ws layout (u16 offsets). Row strides padded: 264/72 u16 (132/36 dwords ≡ 4 mod 32
// -> consecutive rows land on different bank groups for b128 fragment reads).
// WinT[64][264] @0 ; CbX[1024][72] @16896 ; WoX[256][72] @90624 ;
// cnorm fp32[1024] @ byte 218112. Total ~222 KB.
#define WS_WINT 0
#define WS_CBX  16896
#define WS_WOX  90624
#define WS_CN_F 54528   // float index into (float*)ws

__device__ __forceinline__ u16 f2b(float f) {   // RNE float->bf16 bits
  unsigned u = __float_as_uint(f);
  return (u16)((u + 0x7FFFu + ((u >> 16) & 1u)) >> 16);
}
__device__ __forceinline__ f32x4 mfma16(u16x8 a, u16x8 b, f32x4 c) {
  return __builtin_amdgcn_mfma_f32_16x16x32_bf16(
      __builtin_bit_cast(bf16x8, a), __builtin_bit_cast(bf16x8, b), c, 0, 0, 0);
}
// async 16B/lane global->LDS DMA; LDS dst = wave-uniform base + lane*16 (HW rule)
__device__ __forceinline__ void dma16(const u16* g, u16* l) {
  __builtin_amdgcn_global_load_lds(
      (const __attribute__((address_space(1))) unsigned int*)g,
      (__attribute__((address_space(3))) unsigned int*)l, 16, 0, 0);
}

__global__ void nsvq_prep(const float* __restrict__ cb, const float* __restrict__ Win,
                          const float* __restrict__ Wout, u16* __restrict__ wsu) {
  const int g = blockIdx.x * 256 + threadIdx.x;   // 32 blocks -> 8192 threads
  for (int i = g; i < 16384; i += 8192) {          // WinT: Win[c][d] -> [d][c]
    int c = i >> 6, d = i & 63;
    wsu[WS_WINT + d * 264 + c] = f2b(Win[i]);
  }
  for (int i = g; i < 65536; i += 8192) {          // CbX: -2*cb, row-padded
    int k = i >> 6, d = i & 63;
    wsu[WS_CBX + k * 72 + d] = f2b(-2.f * cb[i]);
  }
  for (int i = g; i < 16384; i += 8192) {          // WoX: Wout[d][c] -> [c][d]
    int d = i >> 8, c = i & 255;
    wsu[WS_WOX + c * 72 + d] = f2b(Wout[i]);
  }
  if (g < 1024) {                                  // cnorm (fp32)
    const float4* cr = (const float4*)(cb + (size_t)g * 64);
    float cn = 0.f;
    #pragma unroll
    for (int q = 0; q < 16; ++q) {
      float4 v = cr[q];
      cn = fmaf(v.x, v.x, fmaf(v.y, v.y, fmaf(v.z, v.z, fmaf(v.w, v.w, cn))));
    }
    ((float*)wsu)[WS_CN_F + g] = cn;
  }
}

// Block = 64 tokens, 256 threads (4 waves). Wave w owns tokens [w*16, w*16+16).
// LDS 77 KB -> 2 blocks/CU; 512 blocks = 2/CU.
__global__ __launch_bounds__(256, 2) void nsvq_main(
    const float* __restrict__ in, const float* __restrict__ rnd,
    const float* __restrict__ bin, const float* __restrict__ bout,
    const u16* __restrict__ wsu, const float* __restrict__ cnorm,
    float* __restrict__ out) {
  __shared__ u16 buf[18432];        // 36 KB: WinT(33K) / CbX dbuf(2x18K) / WoX(36K)
  __shared__ u16 InT[64 * 256];     // 32 KB, [t][c] bf16, 16B-block XOR swizzle
  __shared__ u16 Xt[64 * 64];       // 8 KB, [t][d] bf16, swizzled
  __shared__ float mnp[4][64];      // per-wave code-slice mins

  const int tid  = threadIdx.x;
  const int lane = tid & 63;
  const int w    = tid >> 6;                   // 0..3
  const int quad = lane >> 4, col = lane & 15;
  const int b  = blockIdx.x >> 5;              // 512 blocks: 16 b x 32 tiles
  const int t0 = (blockIdx.x & 31) << 6;
  const int myt = w * 16 + col;                // own token row (0..63)

  // ---- stage InT (fp32->bf16, transpose, packed b128 writes); DMA WinT ----
  {
    const float* ib = in + (size_t)b * DIMc * Tt + t0 + lane;   // lane = t
    #pragma unroll
    for (int it = 0; it < 8; ++it) {
      int c0 = w * 64 + it * 8;
      u16x8 pk;
      #pragma unroll
      for (int j = 0; j < 8; ++j) pk[j] = f2b(ib[(size_t)(c0 + j) * Tt]);
      *(u16x8*)(InT + lane * 256 + (((c0 >> 3) ^ (lane & 7)) << 3)) = pk;
    }
  }
  #pragma unroll
  for (int ii = 0; ii < 9; ++ii) {             // WinT = 33792 B = 33 instrs
    int i = w + 4 * ii;
    if (i < 33) dma16(wsu + WS_WINT + i * 512 + lane * 8, buf + i * 512);
  }
  __syncthreads();   // InT + WinT ready

  // ---- encode: X^T = WinT · InT ; acc init = b_in (dwordx4, L2) ----
  f32x4 acc[4];
  {
    u16x8 Bf[8];
    #pragma unroll
    for (int kt = 0; kt < 8; ++kt)
      Bf[kt] = *(const u16x8*)(InT + myt * 256 + (((kt * 4 + quad) ^ (myt & 7)) << 3));
    #pragma unroll
    for (int mt = 0; mt < 4; ++mt) {
      acc[mt] = *(const f32x4*)(bin + mt * 16 + quad * 4);
      #pragma unroll
      for (int kt = 0; kt < 8; ++kt) {
        u16x8 A = *(const u16x8*)(buf + (mt * 16 + col) * 264 + kt * 32 + quad * 8);
        acc[mt] = mfma16(A, Bf[kt], acc[mt]);
      }
    }
  }
  float x2v = 0.f;
  #pragma unroll
  for (int mt = 0; mt < 4; ++mt) {
    u16x4 pk;
    #pragma unroll
    for (int r = 0; r < 4; ++r) { x2v = fmaf(acc[mt][r], acc[mt][r], x2v); pk[r] = f2b(acc[mt][r]); }
    int bk = mt * 2 + (quad >> 1);
    *(u16x4*)(Xt + myt * 64 + ((bk ^ (myt & 7)) << 3) + (quad & 1) * 4) = pk;
  }
  x2v += __shfl_xor(x2v, 16);
  x2v += __shfl_xor(x2v, 32);                  // x2 of token myt in all lanes
  __syncthreads();   // Xt complete; buf free

  // ---- prefetch rnd for own token (hidden under distance loop) ----
  const float* rp = rnd + ((size_t)(b * Tt) + t0 + myt) * Dd;
  f32x4 rv[4];
  #pragma unroll
  for (int mt = 0; mt < 4; ++mt) rv[mt] = *(const f32x4*)(rp + mt * 16 + quad * 4);

  // ---- distances: dbuf codebook chunks; wave w scans 32 codes/chunk ----
  u16x8 Xa[4], Xb[4];
  #pragma unroll
  for (int nt = 0; nt < 4; ++nt) {
    int tr = nt * 16 + col;
    Xa[nt] = *(const u16x8*)(Xt + tr * 64 + ((quad ^ (tr & 7)) << 3));
    Xb[nt] = *(const u16x8*)(Xt + tr * 64 + (((4 + quad) ^ (tr & 7)) << 3));
  }
  float minv[4] = {3.4e38f, 3.4e38f, 3.4e38f, 3.4e38f};
  {
    // chunk 0 DMA (18 instrs of 1 KB = 128 codes x 144 B)
    #pragma unroll
    for (int ii = 0; ii < 5; ++ii) {
      int i = w + 4 * ii;
      if (i < 18) dma16(wsu + WS_CBX + i * 512 + lane * 8, buf + i * 512);
    }
    for (int ch = 0; ch < 8; ++ch) {
      __syncthreads();                         // chunk ch in LDS; prev compute done
      if (ch < 7) {
        const u16* src = wsu + WS_CBX + (ch + 1) * 9216;
        u16* dst = buf + ((ch + 1) & 1) * 9216;
        #pragma unroll
        for (int ii = 0; ii < 5; ++ii) {
          int i = w + 4 * ii;
          if (i < 18) dma16(src + i * 512 + lane * 8, dst + i * 512);
        }
      }
      const u16* cbase = buf + (ch & 1) * 9216;
      #pragma unroll
      for (int ms = 0; ms < 2; ++ms) {
        f32x4 cn = *(const f32x4*)(cnorm + ch * 128 + w * 32 + ms * 16 + quad * 4);
        const u16* ar = cbase + (w * 32 + ms * 16 + col) * 72;
        u16x8 A0 = *(const u16x8*)(ar + quad * 8);
        u16x8 A1 = *(const u16x8*)(ar + 32 + quad * 8);
        #pragma unroll
        for (int nt = 0; nt < 4; ++nt) {
          f32x4 a = cn;                        // dist = cnorm + (-2c)·x
          a = mfma16(A0, Xa[nt], a);
          a = mfma16(A1, Xb[nt], a);
          #pragma unroll
          for (int r = 0; r < 4; ++r) minv[nt] = fminf(minv[nt], a[r]);
        }
      }
    }
  }
  #pragma unroll
  for (int nt = 0; nt < 4; ++nt) {
    float m = minv[nt];
    m = fminf(m, __shfl_xor(m, 16));
    m = fminf(m, __shfl_xor(m, 32));
    mnp[w][nt * 16 + col] = m;                 // all quads write same value
  }
  __syncthreads();   // mnp ready; buf (CbX) free

  // ---- DMA WoX (overlaps scale+q); q-update fully in registers ----
  #pragma unroll
  for (int ii = 0; ii < 9; ++ii) {             // WoX = 36864 B = 36 instrs
    int i = w + 4 * ii;
    dma16(wsu + WS_WOX + i * 512 + lane * 8, buf + i * 512);
  }
  float rr2v = 0.f;
  #pragma unroll
  for (int mt = 0; mt < 4; ++mt)
    #pragma unroll
    for (int r = 0; r < 4; ++r) rr2v = fmaf(rv[mt][r], rv[mt][r], rr2v);
  rr2v += __shfl_xor(rr2v, 16);
  rr2v += __shfl_xor(rr2v, 32);
  float mv = fminf(fminf(mnp[0][myt], mnp[1][myt]), fminf(mnp[2][myt], mnp[3][myt]));
  float r2  = fmaxf(x2v + mv, 0.f);            // ||x - hard||^2
  float scv = sqrtf(r2) / (sqrtf(rr2v) + 1e-12f);
  #pragma unroll
  for (int mt = 0; mt < 4; ++mt) {             // q = x + sc*rnd -> Xt (bf16)
    u16x4 pk;
    #pragma unroll
    for (int r = 0; r < 4; ++r) pk[r] = f2b(fmaf(scv, rv[mt][r], acc[mt][r]));
    int bk = mt * 2 + (quad >> 1);
    *(u16x4*)(Xt + myt * 64 + ((bk ^ (myt & 7)) << 3) + (quad & 1) * 4) = pk;
  }
  __syncthreads();   // WoX ready; Xt q-values visible

  // ---- decode: out = WoX · q + b_out ; M=256, own 16 tokens ----
  u16x8 Q0 = *(const u16x8*)(Xt + myt * 64 + ((quad ^ (myt & 7)) << 3));
  u16x8 Q1 = *(const u16x8*)(Xt + myt * 64 + (((4 + quad) ^ (myt & 7)) << 3));
  float* ob0 = out + (size_t)b * DIMc * Tt + t0 + myt;
  #pragma unroll
  for (int mt = 0; mt < 16; ++mt) {
    f32x4 a = *(const f32x4*)(bout + mt * 16 + quad * 4);
    const u16* ar = buf + (mt * 16 + col) * 72;
    u16x8 A0 = *(const u16x8*)(ar + quad * 8);
    u16x8 A1 = *(const u16x8*)(ar + 32 + quad * 8);
    a = mfma16(A0, Q0, a);
    a = mfma16(A1, Q1, a);
    #pragma unroll
    for (int r = 0; r < 4; ++r) ob0[(size_t)(mt * 16 + quad * 4 + r) * Tt] = a[r];
  }
}

extern "C" void kernel_launch(void* const* d_in, const int* in_sizes, int n_in,
                              void* d_out, int out_size, void* d_ws, size_t ws_size,
                              hipStream_t stream) {
  const float *in = nullptr, *cb = nullptr, *rnd = nullptr, *bin = nullptr, *bout = nullptr;
  const float* w16[2] = {nullptr, nullptr}; int nw = 0;
  for (int i = 0; i < n_in; ++i) {
    switch (in_sizes[i]) {
      case 8388608: in  = (const float*)d_in[i]; break;
      case 65536:   cb  = (const float*)d_in[i]; break;
      case 2097152: rnd = (const float*)d_in[i]; break;
      case 64:      bin = (const float*)d_in[i]; break;
      case 256:     bout= (const float*)d_in[i]; break;
      case 16384:   if (nw < 2) w16[nw++] = (const float*)d_in[i]; break;
      default: break;
    }
  }
  if (!in)  in  = (const float*)d_in[0];
  if (!cb)  cb  = (const float*)d_in[1];
  if (nw < 2) { w16[0] = (const float*)d_in[2]; w16[1] = (const float*)d_in[4]; }
  if (!bin) bin = (const float*)d_in[3];
  if (!bout) bout = (const float*)d_in[5];
  if (!rnd) rnd = (const float*)d_in[6];

  u16* wsu = (u16*)d_ws;
  const float* cnorm = (const float*)d_ws + WS_CN_F;
  float* outp = (float*)d_out;

  nsvq_prep<<<32, 256, 0, stream>>>(cb, w16[0], w16[1], wsu);
  nsvq_main<<<512, 256, 0, stream>>>(in, rnd, bin, bout, wsu, cnorm, outp);
}